// Round 14
// baseline (271.767 us; speedup 1.0000x reference)
//
#include <hip/hip_runtime.h>
#include <hip/hip_bf16.h>
#include <hip/hip_fp16.h>

#define N_NODES 50000
#define N_EDGES 800000
#define C_H 128
#define C_OUT 64
#define NBLK 196          // ceil(50000/256)
#define TSTRIDE 136       // LDS tile row stride in bf16
#define E_PAD 950272      // >= N_EDGES + 3*N_NODES, multiple of 1024
#define MM_BLKS 782       // ceil(50000/64) row-tiles for the XW1 matmul

typedef __attribute__((ext_vector_type(8))) short bf16x8;
typedef __attribute__((ext_vector_type(4))) float f32x4;

static __device__ __forceinline__ float bf_lo(unsigned int u) { return __uint_as_float(u << 16); }
static __device__ __forceinline__ float bf_hi(unsigned int u) { return __uint_as_float(u & 0xffff0000u); }
static __device__ __forceinline__ unsigned short f2bf(float f) {
    __hip_bfloat16 h = __float2bfloat16(f);
    return *(unsigned short*)&h;
}
static __device__ __forceinline__ unsigned int pack2(float a, float b) {
    return (unsigned int)f2bf(a) | ((unsigned int)f2bf(b) << 16);
}
static __device__ __forceinline__ unsigned short f2h_bits(float f) {
    union { __half h; unsigned short u; } c; c.h = __float2half_rn(f); return c.u;
}
static __device__ __forceinline__ float h_bits2f(unsigned short u) {
    union { __half h; unsigned short u; } c; c.u = u; return __half2float(c.h);
}

// ================= prep: hist(+rank) + pack W + zero epay =================
// block ranges: [0,3125) hist | [3125,3413) pack | [3413,4341) zero
__global__ void prep_kernel(const int* __restrict__ dst, int* __restrict__ counts,
                            int* __restrict__ rank,
                            const float* __restrict__ W1, const float* __restrict__ W2,
                            const float* __restrict__ W3, const float* __restrict__ Wd1,
                            const float* __restrict__ Wd2,
                            unsigned short* __restrict__ P1, unsigned short* __restrict__ P2,
                            unsigned short* __restrict__ P3, unsigned short* __restrict__ Pd1,
                            unsigned short* __restrict__ Pd2,
                            unsigned int* __restrict__ epay) {
    int b = blockIdx.x;
    if (b < 3125) {                               // hist over edges, capture rank
        int e = b * 256 + threadIdx.x;
        rank[e] = atomicAdd(&counts[dst[e]], 1);
    } else if (b < 3413) {                        // pack weights
        int idx = (b - 3125) * 256 + threadIdx.x;
        if (idx < 4 * 16384) {
            int which = idx >> 14;
            int r = idx & 16383;
            const float* W = (which == 0) ? W1 : (which == 1) ? W2 : (which == 2) ? W3 : Wd1;
            unsigned short* P = (which == 0) ? P1 : (which == 1) ? P2 : (which == 2) ? P3 : Pd1;
            int j = r & 7, lane = (r >> 3) & 63, t = r >> 9;
            int nb = t & 7, kb = t >> 3;          // NB=8
            int k = kb * 32 + ((lane >> 4) << 3) + j;
            int n = nb * 16 + (lane & 15);
            P[r] = f2bf(W[(size_t)k * 128 + n]);
        } else {
            int r = idx - 65536;
            if (r < 8192) {
                int j = r & 7, lane = (r >> 3) & 63, t = r >> 9;
                int nb = t & 3, kb = t >> 2;      // NB=4
                int k = kb * 32 + ((lane >> 4) << 3) + j;
                int n = nb * 16 + (lane & 15);
                Pd2[r] = f2bf(Wd2[(size_t)k * 64 + n]);
            }
        }
    } else {                                      // zero epay: 928 blocks x 1024 uints
        int i = (b - 3413) * 256 + threadIdx.x;
        *(uint4*)(epay + (size_t)i * 4) = make_uint4(0, 0, 0, 0);
    }
}

// ================= scan phase 1 (+ degree histogram for counting sort) =================
__global__ void __launch_bounds__(256) scan1_kernel(const int* __restrict__ counts,
                                                    int* __restrict__ eblk,
                                                    int* __restrict__ bsum,
                                                    float* __restrict__ dinv,
                                                    int* __restrict__ dtemp,
                                                    int* __restrict__ bhist) {
    __shared__ int ws[4];
    __shared__ int h[64];
    if (threadIdx.x < 64) h[threadIdx.x] = 0;
    int i = blockIdx.x * 256 + threadIdx.x;
    int v = (i < N_NODES) ? counts[i] : 0;
    if (i < N_NODES) dinv[i] = rsqrtf((float)v + 1.0f);
    int vp = (v + 3) & ~3;                        // padded degree
    int lane = threadIdx.x & 63, w = threadIdx.x >> 6;
    int x = vp;
    #pragma unroll
    for (int off = 1; off < 64; off <<= 1) {
        int t = __shfl_up(x, off, 64);
        if (lane >= off) x += t;
    }
    if (lane == 63) ws[w] = x;
    __syncthreads();                              // covers h init + ws
    if (i < N_NODES) {                            // degree-bin rank within this block
        int bin = min(v, 63);
        dtemp[i] = atomicAdd(&h[bin], 1);
    }
    if (threadIdx.x == 0) {
        int run = 0;
        #pragma unroll
        for (int k = 0; k < 4; ++k) { int t = ws[k]; ws[k] = run; run += t; }
        bsum[blockIdx.x] = run;
    }
    __syncthreads();
    if (i < N_NODES) eblk[i] = x - vp + ws[w];
    if (threadIdx.x < 64) bhist[blockIdx.x * 64 + threadIdx.x] = h[threadIdx.x];
}

// ================= scan phase 2 (+ per-bin column prefix for sort) =================
__global__ void __launch_bounds__(256) scan2_kernel(const int* __restrict__ bsum,
                                                    int* __restrict__ bo,
                                                    int* __restrict__ rowptr,
                                                    int* __restrict__ bhist) {
    __shared__ int ws[4];
    int i = threadIdx.x;
    int v = (i < NBLK) ? bsum[i] : 0;
    int lane = i & 63, w = i >> 6;
    int x = v;
    #pragma unroll
    for (int off = 1; off < 64; off <<= 1) {
        int t = __shfl_up(x, off, 64);
        if (lane >= off) x += t;
    }
    if (lane == 63) ws[w] = x;
    __syncthreads();
    if (i == 0) {
        int run = 0;
        #pragma unroll
        for (int k = 0; k < 4; ++k) { int t = ws[k]; ws[k] = run; run += t; }
    }
    __syncthreads();
    int excl = x - v + ws[w];
    if (i < NBLK) bo[i] = excl;
    if (i == 255) rowptr[N_NODES] = excl + v;

    // counting-sort offsets: wave 0 only (threads 0..63 = one wave)
    if (threadIdx.x < 64) {
        int j = threadIdx.x;
        int run = 0;
        for (int b = 0; b < NBLK; ++b) {
            int t = bhist[b * 64 + j];
            bhist[b * 64 + j] = run;
            run += t;
        }
        int x2 = run;                              // bin totals -> exclusive scan over bins
        #pragma unroll
        for (int off = 1; off < 64; off <<= 1) {
            int t = __shfl_up(x2, off, 64);
            if (j >= off) x2 += t;
        }
        int base = x2 - run;
        for (int b = 0; b < NBLK; ++b) bhist[b * 64 + j] += base;
    }
}

// ================= scan phase 3 (+ perm scatter) =================
__global__ void scan3_kernel(const int* __restrict__ eblk, const int* __restrict__ bo,
                             int* __restrict__ rowptr,
                             const int* __restrict__ counts, const int* __restrict__ dtemp,
                             const int* __restrict__ bhist, int* __restrict__ perm) {
    int i = blockIdx.x * 256 + threadIdx.x;
    if (i < N_NODES) {
        rowptr[i] = eblk[i] + bo[blockIdx.x];
        int bin = min(counts[i], 63);
        perm[bhist[blockIdx.x * 64 + bin] + dtemp[i]] = i;
    }
}

// ================= heterogeneous: XW1 matmul + csr fill =================
__global__ void __launch_bounds__(256) fill_mm_kernel(
        const float* __restrict__ x, const unsigned short* __restrict__ P1,
        unsigned short* __restrict__ XW1,
        const int* __restrict__ src, const int* __restrict__ dst,
        const float* __restrict__ dinv,
        const int* __restrict__ rowptr, const int* __restrict__ rank,
        unsigned int* __restrict__ epay) {
    int b = blockIdx.x;
    if (b < MM_BLKS) {
        const int lane = threadIdx.x & 63;
        const int wave = threadIdx.x >> 6;
        const int wid  = b * 4 + wave;
        if (wid * 16 >= N_NODES) return;
        const int node = wid * 16 + (lane & 15);
        const int quad = lane >> 4;
        f32x4 acc[8];
        #pragma unroll
        for (int nb = 0; nb < 8; ++nb) acc[nb] = (f32x4){0.f, 0.f, 0.f, 0.f};
        #pragma unroll
        for (int kb = 0; kb < 4; ++kb) {
            const float* p = x + (size_t)node * 128 + kb * 32 + quad * 8;
            float4 lo = *(const float4*)p;
            float4 hi = *(const float4*)(p + 4);
            union { bf16x8 v; unsigned int u[4]; } tmp;
            tmp.u[0] = pack2(lo.x, lo.y); tmp.u[1] = pack2(lo.z, lo.w);
            tmp.u[2] = pack2(hi.x, hi.y); tmp.u[3] = pack2(hi.z, hi.w);
            #pragma unroll
            for (int nb = 0; nb < 8; ++nb) {
                bf16x8 wf = *(const bf16x8*)(P1 + ((size_t)(kb * 8 + nb) * 64 + lane) * 8);
                acc[nb] = __builtin_amdgcn_mfma_f32_16x16x32_bf16(wf, tmp.v, acc[nb], 0, 0, 0);
            }
        }
        #pragma unroll
        for (int nb = 0; nb < 8; ++nb) {
            int ch = nb * 16 + quad * 4;
            uint2 o;
            o.x = pack2(acc[nb][0], acc[nb][1]);
            o.y = pack2(acc[nb][2], acc[nb][3]);
            *(uint2*)(XW1 + (size_t)node * C_H + ch) = o;
        }
    } else {
        int e = (b - MM_BLKS) * 256 + threadIdx.x;
        if (e < N_EDGES) {
            int d = dst[e], s = src[e];
            int pos = rowptr[d] + rank[e];
            float nrm = dinv[s] * dinv[d];
            epay[pos] = (unsigned int)s | ((unsigned int)f2h_bits(nrm) << 16);
        }
    }
}

// ---- shared gather core: 16 lanes per node row, 8 channels per lane,
//      8 edges per iter + 4-edge tail (r11 known-good form) ----
static __device__ __forceinline__ void gather_row(
        const unsigned int* __restrict__ epay,
        const unsigned short* __restrict__ hin,
        int beg, int end, int c8, float dii, uint4 selfraw, float* a) {
    a[0] = bf_lo(selfraw.x) * dii; a[1] = bf_hi(selfraw.x) * dii;
    a[2] = bf_lo(selfraw.y) * dii; a[3] = bf_hi(selfraw.y) * dii;
    a[4] = bf_lo(selfraw.z) * dii; a[5] = bf_hi(selfraw.z) * dii;
    a[6] = bf_lo(selfraw.w) * dii; a[7] = bf_hi(selfraw.w) * dii;
    int p = beg;
    for (; p + 8 <= end; p += 8) {
        uint4 ev0 = *(const uint4*)(epay + p);
        uint4 ev1 = *(const uint4*)(epay + p + 4);
        unsigned int ee[8] = {ev0.x, ev0.y, ev0.z, ev0.w, ev1.x, ev1.y, ev1.z, ev1.w};
        uint4 rv[8];
        #pragma unroll
        for (int j = 0; j < 8; ++j)
            rv[j] = *(const uint4*)(hin + (size_t)(ee[j] & 0xffffu) * C_H + c8);
        #pragma unroll
        for (int j = 0; j < 8; ++j) {
            float nm = h_bits2f((unsigned short)(ee[j] >> 16));
            a[0] = fmaf(bf_lo(rv[j].x), nm, a[0]); a[1] = fmaf(bf_hi(rv[j].x), nm, a[1]);
            a[2] = fmaf(bf_lo(rv[j].y), nm, a[2]); a[3] = fmaf(bf_hi(rv[j].y), nm, a[3]);
            a[4] = fmaf(bf_lo(rv[j].z), nm, a[4]); a[5] = fmaf(bf_hi(rv[j].z), nm, a[5]);
            a[6] = fmaf(bf_lo(rv[j].w), nm, a[6]); a[7] = fmaf(bf_hi(rv[j].w), nm, a[7]);
        }
    }
    if (p < end) {                                // exactly 4 remain
        uint4 ev = *(const uint4*)(epay + p);
        unsigned int ee[4] = {ev.x, ev.y, ev.z, ev.w};
        uint4 rv[4];
        #pragma unroll
        for (int j = 0; j < 4; ++j)
            rv[j] = *(const uint4*)(hin + (size_t)(ee[j] & 0xffffu) * C_H + c8);
        #pragma unroll
        for (int j = 0; j < 4; ++j) {
            float nm = h_bits2f((unsigned short)(ee[j] >> 16));
            a[0] = fmaf(bf_lo(rv[j].x), nm, a[0]); a[1] = fmaf(bf_hi(rv[j].x), nm, a[1]);
            a[2] = fmaf(bf_lo(rv[j].y), nm, a[2]); a[3] = fmaf(bf_hi(rv[j].y), nm, a[3]);
            a[4] = fmaf(bf_lo(rv[j].z), nm, a[4]); a[5] = fmaf(bf_hi(rv[j].z), nm, a[5]);
            a[6] = fmaf(bf_lo(rv[j].w), nm, a[6]); a[7] = fmaf(bf_hi(rv[j].w), nm, a[7]);
        }
    }
}

// ================= layer 1: pure gather(XW1) + bias + relu -> bf16 =================
__global__ void __launch_bounds__(256) gather1_kernel(
        const int* __restrict__ rowptr,
        const unsigned int* __restrict__ epay,
        const float* __restrict__ dinv,
        const int* __restrict__ perm,
        const unsigned short* __restrict__ hin,
        const float* __restrict__ bias,
        unsigned short* __restrict__ out) {
    int t    = blockIdx.x * 256 + threadIdx.x;
    int node = perm[t >> 4];                      // degree-sorted order
    int c8   = (t & 15) << 3;

    float di = dinv[node];
    uint4 raw = *(const uint4*)(hin + (size_t)node * C_H + c8);
    float a[8];
    gather_row(epay, hin, rowptr[node], rowptr[node + 1], c8, di * di, raw, a);

    float4 ba = *(const float4*)(bias + c8);
    float4 bb = *(const float4*)(bias + c8 + 4);
    a[0] = fmaxf(a[0] + ba.x, 0.f); a[1] = fmaxf(a[1] + ba.y, 0.f);
    a[2] = fmaxf(a[2] + ba.z, 0.f); a[3] = fmaxf(a[3] + ba.w, 0.f);
    a[4] = fmaxf(a[4] + bb.x, 0.f); a[5] = fmaxf(a[5] + bb.y, 0.f);
    a[6] = fmaxf(a[6] + bb.z, 0.f); a[7] = fmaxf(a[7] + bb.w, 0.f);
    uint4 o;
    o.x = pack2(a[0], a[1]); o.y = pack2(a[2], a[3]);
    o.z = pack2(a[4], a[5]); o.w = pack2(a[6], a[7]);
    *(uint4*)(out + (size_t)node * C_H + c8) = o;
}

// ================= fused layer: gather(A·H) -> LDS tile -> MFMA chain =================
template <bool FINAL>
__global__ void __launch_bounds__(256) fused_layer_kernel(
        const int* __restrict__ rowptr,
        const unsigned int* __restrict__ epay,
        const float* __restrict__ dinv,
        const int* __restrict__ perm,
        const unsigned short* __restrict__ hin,
        const unsigned short* __restrict__ Wp,
        const float* __restrict__ bias,
        const unsigned short* __restrict__ Wd1p,
        const float* __restrict__ bd1,
        const unsigned short* __restrict__ Wd2p,
        const float* __restrict__ bd2,
        unsigned short* __restrict__ out_b,
        float* __restrict__ out_f) {
    __shared__ unsigned short sG[16 * TSTRIDE];
    const int t = threadIdx.x;

    // ---- phase A: gather agg row into LDS tile (degree-sorted nodes) ----
    {
        int nl = t >> 4, c8 = (t & 15) << 3;
        int nd = perm[blockIdx.x * 16 + nl];
        float di = dinv[nd];
        uint4 raw = *(const uint4*)(hin + (size_t)nd * C_H + c8);
        float a[8];
        gather_row(epay, hin, rowptr[nd], rowptr[nd + 1], c8, di * di, raw, a);
        uint4 o;
        o.x = pack2(a[0], a[1]); o.y = pack2(a[2], a[3]);
        o.z = pack2(a[4], a[5]); o.w = pack2(a[6], a[7]);
        *(uint4*)(sG + nl * TSTRIDE + c8) = o;
    }
    __syncthreads();

    const int lane = t & 63, wave = t >> 6, quad = lane >> 4, row = lane & 15;
    const int node = perm[blockIdx.x * 16 + row];

    // ---- mm1: tile @ Wp (COUT=128), bias+relu ----
    f32x4 acc0 = (f32x4){0.f, 0.f, 0.f, 0.f};
    f32x4 acc1 = (f32x4){0.f, 0.f, 0.f, 0.f};
    const int nb0 = 2 * wave, nb1 = 2 * wave + 1;
    #pragma unroll
    for (int kb = 0; kb < 4; ++kb) {
        bf16x8 hf = *(const bf16x8*)(sG + row * TSTRIDE + kb * 32 + quad * 8);
        bf16x8 wf0 = *(const bf16x8*)(Wp + ((size_t)(kb * 8 + nb0) * 64 + lane) * 8);
        bf16x8 wf1 = *(const bf16x8*)(Wp + ((size_t)(kb * 8 + nb1) * 64 + lane) * 8);
        acc0 = __builtin_amdgcn_mfma_f32_16x16x32_bf16(wf0, hf, acc0, 0, 0, 0);
        acc1 = __builtin_amdgcn_mfma_f32_16x16x32_bf16(wf1, hf, acc1, 0, 0, 0);
    }
    float4 ba0 = *(const float4*)(bias + nb0 * 16 + quad * 4);
    float4 ba1 = *(const float4*)(bias + nb1 * 16 + quad * 4);
    float v00 = fmaxf(acc0[0] + ba0.x, 0.f), v01 = fmaxf(acc0[1] + ba0.y, 0.f);
    float v02 = fmaxf(acc0[2] + ba0.z, 0.f), v03 = fmaxf(acc0[3] + ba0.w, 0.f);
    float v10 = fmaxf(acc1[0] + ba1.x, 0.f), v11 = fmaxf(acc1[1] + ba1.y, 0.f);
    float v12 = fmaxf(acc1[2] + ba1.z, 0.f), v13 = fmaxf(acc1[3] + ba1.w, 0.f);

    if (!FINAL) {
        uint2 o0, o1;
        o0.x = pack2(v00, v01); o0.y = pack2(v02, v03);
        o1.x = pack2(v10, v11); o1.y = pack2(v12, v13);
        *(uint2*)(out_b + (size_t)node * C_H + nb0 * 16 + quad * 4) = o0;
        *(uint2*)(out_b + (size_t)node * C_H + nb1 * 16 + quad * 4) = o1;
        return;
    }

    // ---- FINAL: H3 -> tile -> Wd1 -> tile -> Wd2 -> sigmoid -> out_f ----
    __syncthreads();
    {
        uint2 o0, o1;
        o0.x = pack2(v00, v01); o0.y = pack2(v02, v03);
        o1.x = pack2(v10, v11); o1.y = pack2(v12, v13);
        *(uint2*)(sG + row * TSTRIDE + nb0 * 16 + quad * 4) = o0;
        *(uint2*)(sG + row * TSTRIDE + nb1 * 16 + quad * 4) = o1;
    }
    __syncthreads();

    acc0 = (f32x4){0.f, 0.f, 0.f, 0.f};
    acc1 = (f32x4){0.f, 0.f, 0.f, 0.f};
    #pragma unroll
    for (int kb = 0; kb < 4; ++kb) {
        bf16x8 hf = *(const bf16x8*)(sG + row * TSTRIDE + kb * 32 + quad * 8);
        bf16x8 wf0 = *(const bf16x8*)(Wd1p + ((size_t)(kb * 8 + nb0) * 64 + lane) * 8);
        bf16x8 wf1 = *(const bf16x8*)(Wd1p + ((size_t)(kb * 8 + nb1) * 64 + lane) * 8);
        acc0 = __builtin_amdgcn_mfma_f32_16x16x32_bf16(wf0, hf, acc0, 0, 0, 0);
        acc1 = __builtin_amdgcn_mfma_f32_16x16x32_bf16(wf1, hf, acc1, 0, 0, 0);
    }
    ba0 = *(const float4*)(bd1 + nb0 * 16 + quad * 4);
    ba1 = *(const float4*)(bd1 + nb1 * 16 + quad * 4);
    v00 = fmaxf(acc0[0] + ba0.x, 0.f); v01 = fmaxf(acc0[1] + ba0.y, 0.f);
    v02 = fmaxf(acc0[2] + ba0.z, 0.f); v03 = fmaxf(acc0[3] + ba0.w, 0.f);
    v10 = fmaxf(acc1[0] + ba1.x, 0.f); v11 = fmaxf(acc1[1] + ba1.y, 0.f);
    v12 = fmaxf(acc1[2] + ba1.z, 0.f); v13 = fmaxf(acc1[3] + ba1.w, 0.f);
    __syncthreads();
    {
        uint2 o0, o1;
        o0.x = pack2(v00, v01); o0.y = pack2(v02, v03);
        o1.x = pack2(v10, v11); o1.y = pack2(v12, v13);
        *(uint2*)(sG + row * TSTRIDE + nb0 * 16 + quad * 4) = o0;
        *(uint2*)(sG + row * TSTRIDE + nb1 * 16 + quad * 4) = o1;
    }
    __syncthreads();

    f32x4 acc = (f32x4){0.f, 0.f, 0.f, 0.f};
    #pragma unroll
    for (int kb = 0; kb < 4; ++kb) {
        bf16x8 hf = *(const bf16x8*)(sG + row * TSTRIDE + kb * 32 + quad * 8);
        bf16x8 wf = *(const bf16x8*)(Wd2p + ((size_t)(kb * 4 + wave) * 64 + lane) * 8);
        acc = __builtin_amdgcn_mfma_f32_16x16x32_bf16(wf, hf, acc, 0, 0, 0);
    }
    int ch = wave * 16 + quad * 4;
    float4 b4 = *(const float4*)(bd2 + ch);
    float4 r;
    r.x = 1.f / (1.f + expf(-(acc[0] + b4.x)));
    r.y = 1.f / (1.f + expf(-(acc[1] + b4.y)));
    r.z = 1.f / (1.f + expf(-(acc[2] + b4.z)));
    r.w = 1.f / (1.f + expf(-(acc[3] + b4.w)));
    *(float4*)(out_f + (size_t)node * C_OUT + ch) = r;
}

extern "C" void kernel_launch(void* const* d_in, const int* in_sizes, int n_in,
                              void* d_out, int out_size, void* d_ws, size_t ws_size,
                              hipStream_t stream) {
    const float* x   = (const float*)d_in[0];
    const int*   ei  = (const int*)d_in[1];
    const float* W1  = (const float*)d_in[2];
    const float* b1  = (const float*)d_in[3];
    const float* W2  = (const float*)d_in[4];
    const float* b2  = (const float*)d_in[5];
    const float* W3  = (const float*)d_in[6];
    const float* b3  = (const float*)d_in[7];
    const float* Wd1 = (const float*)d_in[8];
    const float* bd1 = (const float*)d_in[9];
    const float* Wd2 = (const float*)d_in[10];
    const float* bd2 = (const float*)d_in[11];

    const int* src = ei;
    const int* dst = ei + N_EDGES;

    char* base = (char*)d_ws;
    size_t off = 0;
    auto alloc = [&](size_t bytes) { char* p = base + off; off += (bytes + 255) & ~size_t(255); return p; };
    int*            counts = (int*)alloc(50176 * 4);
    unsigned int*   epay   = (unsigned int*)alloc((size_t)E_PAD * 4);
    int*            rank   = (int*)alloc((size_t)N_EDGES * 4);
    float*          dinv   = (float*)alloc(N_NODES * 4);
    int*            rowptr = (int*)alloc((N_NODES + 1) * 4);
    int*            eblk   = (int*)alloc(N_NODES * 4);
    int*            bsum   = (int*)alloc(256 * 4);
    int*            bo     = (int*)alloc(256 * 4);
    int*            dtemp  = (int*)alloc(N_NODES * 4);
    int*            bhist  = (int*)alloc(NBLK * 64 * 4);
    int*            perm   = (int*)alloc(N_NODES * 4);
    unsigned short* XW1    = (unsigned short*)alloc((size_t)N_NODES * C_H * 2);
    unsigned short* bufA   = (unsigned short*)alloc((size_t)N_NODES * C_H * 2);
    unsigned short* bufB   = (unsigned short*)alloc((size_t)N_NODES * C_H * 2);
    unsigned short* P1     = (unsigned short*)alloc(128 * 128 * 2);
    unsigned short* P2     = (unsigned short*)alloc(128 * 128 * 2);
    unsigned short* P3     = (unsigned short*)alloc(128 * 128 * 2);
    unsigned short* Pd1    = (unsigned short*)alloc(128 * 128 * 2);
    unsigned short* Pd2    = (unsigned short*)alloc(128 * 64 * 2);

    const int T = 256;
    dim3 blk(T);
    dim3 gN((N_NODES + T - 1) / T);            // 196
    dim3 gPrep(3125 + 288 + E_PAD / 1024);     // hist + pack + zero (928)
    dim3 gFillMM(MM_BLKS + 3125);              // mm + fill
    dim3 gFused(N_NODES / 16);                 // 3125, exact

    hipMemsetAsync(counts, 0, 50176 * 4, stream);
    prep_kernel<<<gPrep, blk, 0, stream>>>(dst, counts, rank,
                                           W1, W2, W3, Wd1, Wd2,
                                           P1, P2, P3, Pd1, Pd2, epay);
    scan1_kernel<<<gN, blk, 0, stream>>>(counts, eblk, bsum, dinv, dtemp, bhist);
    scan2_kernel<<<1, blk, 0, stream>>>(bsum, bo, rowptr, bhist);
    scan3_kernel<<<gN, blk, 0, stream>>>(eblk, bo, rowptr, counts, dtemp, bhist, perm);
    fill_mm_kernel<<<gFillMM, blk, 0, stream>>>(x, P1, XW1, src, dst, dinv,
                                                rowptr, rank, epay);

    // ---- layer 1: relu(agg(XW1) + b1) -> bufA (pure gather, degree-sorted) ----
    gather1_kernel<<<gFused, blk, 0, stream>>>(rowptr, epay, dinv, perm, XW1, b1, bufA);
    // ---- layer 2 ----
    fused_layer_kernel<false><<<gFused, blk, 0, stream>>>(
        rowptr, epay, dinv, perm, bufA, P2, b2, nullptr, nullptr, nullptr, nullptr, bufB, nullptr);
    // ---- layer 3 + dense head ----
    fused_layer_kernel<true><<<gFused, blk, 0, stream>>>(
        rowptr, epay, dinv, perm, bufB, P3, b3, Pd1, bd1, Pd2, bd2, nullptr, (float*)d_out);
}

// Round 15
// 255.006 us; speedup vs baseline: 1.0657x; 1.0657x over previous
//
#include <hip/hip_runtime.h>
#include <hip/hip_bf16.h>
#include <hip/hip_fp16.h>

#define N_NODES 50000
#define N_EDGES 800000
#define C_H 128
#define C_OUT 64
#define NBLK 196          // ceil(50000/256)
#define TSTRIDE 136       // LDS tile row stride in bf16
#define E_PAD 950272      // >= N_EDGES + 3*N_NODES, 1024-aligned
#define MM_BLKS 782       // ceil(50000/64) row-tiles for the XW1 matmul

typedef __attribute__((ext_vector_type(8))) short bf16x8;
typedef __attribute__((ext_vector_type(4))) float f32x4;

static __device__ __forceinline__ float bf_lo(unsigned int u) { return __uint_as_float(u << 16); }
static __device__ __forceinline__ float bf_hi(unsigned int u) { return __uint_as_float(u & 0xffff0000u); }
static __device__ __forceinline__ unsigned short f2bf(float f) {
    __hip_bfloat16 h = __float2bfloat16(f);
    return *(unsigned short*)&h;
}
static __device__ __forceinline__ unsigned int pack2(float a, float b) {
    return (unsigned int)f2bf(a) | ((unsigned int)f2bf(b) << 16);
}
static __device__ __forceinline__ unsigned short f2h_bits(float f) {
    union { __half h; unsigned short u; } c; c.h = __float2half_rn(f); return c.u;
}
static __device__ __forceinline__ float h_bits2f(unsigned short u) {
    union { __half h; unsigned short u; } c; c.u = u; return __half2float(c.h);
}

// ================= prep: hist(+rank) + pack W + zero epay =================
// block ranges: [0,3125) hist | [3125,3413) pack | [3413,4341) zero
__global__ void prep_kernel(const int* __restrict__ dst, int* __restrict__ counts,
                            int* __restrict__ rank,
                            const float* __restrict__ W1, const float* __restrict__ W2,
                            const float* __restrict__ W3, const float* __restrict__ Wd1,
                            const float* __restrict__ Wd2,
                            unsigned short* __restrict__ P1, unsigned short* __restrict__ P2,
                            unsigned short* __restrict__ P3, unsigned short* __restrict__ Pd1,
                            unsigned short* __restrict__ Pd2,
                            unsigned int* __restrict__ epay) {
    int b = blockIdx.x;
    if (b < 3125) {                               // hist over edges, capture rank
        int e = b * 256 + threadIdx.x;
        rank[e] = atomicAdd(&counts[dst[e]], 1);
    } else if (b < 3413) {                        // pack weights
        int idx = (b - 3125) * 256 + threadIdx.x;
        if (idx < 4 * 16384) {
            int which = idx >> 14;
            int r = idx & 16383;
            const float* W = (which == 0) ? W1 : (which == 1) ? W2 : (which == 2) ? W3 : Wd1;
            unsigned short* P = (which == 0) ? P1 : (which == 1) ? P2 : (which == 2) ? P3 : Pd1;
            int j = r & 7, lane = (r >> 3) & 63, t = r >> 9;
            int nb = t & 7, kb = t >> 3;          // NB=8
            int k = kb * 32 + ((lane >> 4) << 3) + j;
            int n = nb * 16 + (lane & 15);
            P[r] = f2bf(W[(size_t)k * 128 + n]);
        } else {
            int r = idx - 65536;
            if (r < 8192) {
                int j = r & 7, lane = (r >> 3) & 63, t = r >> 9;
                int nb = t & 3, kb = t >> 2;      // NB=4
                int k = kb * 32 + ((lane >> 4) << 3) + j;
                int n = nb * 16 + (lane & 15);
                Pd2[r] = f2bf(Wd2[(size_t)k * 64 + n]);
            }
        }
    } else {                                      // zero epay: 928 blocks x 1024 uints
        int i = (b - 3413) * 256 + threadIdx.x;
        *(uint4*)(epay + (size_t)i * 4) = make_uint4(0, 0, 0, 0);
    }
}

// ================= CSR scans (degree padded to multiple of 4) =================
__global__ void __launch_bounds__(256) scan1_kernel(const int* __restrict__ counts,
                                                    int* __restrict__ eblk,
                                                    int* __restrict__ bsum,
                                                    float* __restrict__ dinv) {
    __shared__ int ws[4];
    int i = blockIdx.x * 256 + threadIdx.x;
    int v = (i < N_NODES) ? counts[i] : 0;
    if (i < N_NODES) dinv[i] = rsqrtf((float)v + 1.0f);
    int vp = (v + 3) & ~3;                        // padded degree
    int lane = threadIdx.x & 63, w = threadIdx.x >> 6;
    int x = vp;
    #pragma unroll
    for (int off = 1; off < 64; off <<= 1) {
        int t = __shfl_up(x, off, 64);
        if (lane >= off) x += t;
    }
    if (lane == 63) ws[w] = x;
    __syncthreads();
    if (threadIdx.x == 0) {
        int run = 0;
        #pragma unroll
        for (int k = 0; k < 4; ++k) { int t = ws[k]; ws[k] = run; run += t; }
        bsum[blockIdx.x] = run;
    }
    __syncthreads();
    if (i < N_NODES) eblk[i] = x - vp + ws[w];
}

__global__ void __launch_bounds__(256) scan2_kernel(const int* __restrict__ bsum,
                                                    int* __restrict__ bo,
                                                    int* __restrict__ rowptr) {
    __shared__ int ws[4];
    int i = threadIdx.x;
    int v = (i < NBLK) ? bsum[i] : 0;
    int lane = i & 63, w = i >> 6;
    int x = v;
    #pragma unroll
    for (int off = 1; off < 64; off <<= 1) {
        int t = __shfl_up(x, off, 64);
        if (lane >= off) x += t;
    }
    if (lane == 63) ws[w] = x;
    __syncthreads();
    if (i == 0) {
        int run = 0;
        #pragma unroll
        for (int k = 0; k < 4; ++k) { int t = ws[k]; ws[k] = run; run += t; }
    }
    __syncthreads();
    int excl = x - v + ws[w];
    if (i < NBLK) bo[i] = excl;
    if (i == 255) rowptr[N_NODES] = excl + v;
}

__global__ void scan3_kernel(const int* __restrict__ eblk, const int* __restrict__ bo,
                             int* __restrict__ rowptr) {
    int i = blockIdx.x * 256 + threadIdx.x;
    if (i < N_NODES) rowptr[i] = eblk[i] + bo[blockIdx.x];
}

// ================= heterogeneous: XW1 matmul + csr fill =================
// blocks [0, MM_BLKS): XW1 = x(fp32) @ P1 -> bf16 (no bias; fill's idle slots hide it)
// blocks [MM_BLKS, MM_BLKS+3125): epay[rowptr[d]+rank[e]] = {u16 src, f16 norm}
__global__ void __launch_bounds__(256) fill_mm_kernel(
        const float* __restrict__ x, const unsigned short* __restrict__ P1,
        unsigned short* __restrict__ XW1,
        const int* __restrict__ src, const int* __restrict__ dst,
        const float* __restrict__ dinv,
        const int* __restrict__ rowptr, const int* __restrict__ rank,
        unsigned int* __restrict__ epay) {
    int b = blockIdx.x;
    if (b < MM_BLKS) {
        const int lane = threadIdx.x & 63;
        const int wave = threadIdx.x >> 6;
        const int wid  = b * 4 + wave;
        if (wid * 16 >= N_NODES) return;          // exact: 3125 waves used
        const int node = wid * 16 + (lane & 15);
        const int quad = lane >> 4;
        f32x4 acc[8];
        #pragma unroll
        for (int nb = 0; nb < 8; ++nb) acc[nb] = (f32x4){0.f, 0.f, 0.f, 0.f};
        #pragma unroll
        for (int kb = 0; kb < 4; ++kb) {
            const float* p = x + (size_t)node * 128 + kb * 32 + quad * 8;
            float4 lo = *(const float4*)p;
            float4 hi = *(const float4*)(p + 4);
            union { bf16x8 v; unsigned int u[4]; } tmp;
            tmp.u[0] = pack2(lo.x, lo.y); tmp.u[1] = pack2(lo.z, lo.w);
            tmp.u[2] = pack2(hi.x, hi.y); tmp.u[3] = pack2(hi.z, hi.w);
            #pragma unroll
            for (int nb = 0; nb < 8; ++nb) {
                bf16x8 wf = *(const bf16x8*)(P1 + ((size_t)(kb * 8 + nb) * 64 + lane) * 8);
                acc[nb] = __builtin_amdgcn_mfma_f32_16x16x32_bf16(wf, tmp.v, acc[nb], 0, 0, 0);
            }
        }
        #pragma unroll
        for (int nb = 0; nb < 8; ++nb) {
            int ch = nb * 16 + quad * 4;
            uint2 o;
            o.x = pack2(acc[nb][0], acc[nb][1]);
            o.y = pack2(acc[nb][2], acc[nb][3]);
            *(uint2*)(XW1 + (size_t)node * C_H + ch) = o;
        }
    } else {
        int e = (b - MM_BLKS) * 256 + threadIdx.x;
        if (e < N_EDGES) {
            int d = dst[e], s = src[e];
            int pos = rowptr[d] + rank[e];
            float nrm = dinv[s] * dinv[d];
            epay[pos] = (unsigned int)s | ((unsigned int)f2h_bits(nrm) << 16);
        }
    }
}

// ================= layer 1: pure gather(XW1) + bias + relu -> bf16 =================
__global__ void __launch_bounds__(256) gather1_kernel(
        const int* __restrict__ rowptr,
        const unsigned int* __restrict__ epay,
        const float* __restrict__ dinv,
        const unsigned short* __restrict__ hin,
        const float* __restrict__ bias,
        unsigned short* __restrict__ out) {
    int t    = blockIdx.x * 256 + threadIdx.x;
    int node = t >> 4;
    int c8   = (t & 15) << 3;

    float di = dinv[node], dii = di * di;
    uint4 raw = *(const uint4*)(hin + (size_t)node * C_H + c8);
    float a0 = bf_lo(raw.x) * dii, a1 = bf_hi(raw.x) * dii;
    float a2 = bf_lo(raw.y) * dii, a3 = bf_hi(raw.y) * dii;
    float a4 = bf_lo(raw.z) * dii, a5 = bf_hi(raw.z) * dii;
    float a6 = bf_lo(raw.w) * dii, a7 = bf_hi(raw.w) * dii;
    int beg = rowptr[node], end = rowptr[node + 1];
    int p = beg;
    for (; p + 8 <= end; p += 8) {
        uint4 ev0 = *(const uint4*)(epay + p);
        uint4 ev1 = *(const uint4*)(epay + p + 4);
        unsigned int ee[8] = {ev0.x, ev0.y, ev0.z, ev0.w, ev1.x, ev1.y, ev1.z, ev1.w};
        uint4 rv[8];
        #pragma unroll
        for (int j = 0; j < 8; ++j)
            rv[j] = *(const uint4*)(hin + (size_t)(ee[j] & 0xffffu) * C_H + c8);
        #pragma unroll
        for (int j = 0; j < 8; ++j) {
            float nm = h_bits2f((unsigned short)(ee[j] >> 16));
            a0 = fmaf(bf_lo(rv[j].x), nm, a0); a1 = fmaf(bf_hi(rv[j].x), nm, a1);
            a2 = fmaf(bf_lo(rv[j].y), nm, a2); a3 = fmaf(bf_hi(rv[j].y), nm, a3);
            a4 = fmaf(bf_lo(rv[j].z), nm, a4); a5 = fmaf(bf_hi(rv[j].z), nm, a5);
            a6 = fmaf(bf_lo(rv[j].w), nm, a6); a7 = fmaf(bf_hi(rv[j].w), nm, a7);
        }
    }
    if (p < end) {
        uint4 ev = *(const uint4*)(epay + p);
        unsigned int ee[4] = {ev.x, ev.y, ev.z, ev.w};
        uint4 rv[4];
        #pragma unroll
        for (int j = 0; j < 4; ++j)
            rv[j] = *(const uint4*)(hin + (size_t)(ee[j] & 0xffffu) * C_H + c8);
        #pragma unroll
        for (int j = 0; j < 4; ++j) {
            float nm = h_bits2f((unsigned short)(ee[j] >> 16));
            a0 = fmaf(bf_lo(rv[j].x), nm, a0); a1 = fmaf(bf_hi(rv[j].x), nm, a1);
            a2 = fmaf(bf_lo(rv[j].y), nm, a2); a3 = fmaf(bf_hi(rv[j].y), nm, a3);
            a4 = fmaf(bf_lo(rv[j].z), nm, a4); a5 = fmaf(bf_hi(rv[j].z), nm, a5);
            a6 = fmaf(bf_lo(rv[j].w), nm, a6); a7 = fmaf(bf_hi(rv[j].w), nm, a7);
        }
    }
    float4 ba = *(const float4*)(bias + c8);
    float4 bb = *(const float4*)(bias + c8 + 4);
    a0 = fmaxf(a0 + ba.x, 0.f); a1 = fmaxf(a1 + ba.y, 0.f);
    a2 = fmaxf(a2 + ba.z, 0.f); a3 = fmaxf(a3 + ba.w, 0.f);
    a4 = fmaxf(a4 + bb.x, 0.f); a5 = fmaxf(a5 + bb.y, 0.f);
    a6 = fmaxf(a6 + bb.z, 0.f); a7 = fmaxf(a7 + bb.w, 0.f);
    uint4 o;
    o.x = pack2(a0, a1); o.y = pack2(a2, a3);
    o.z = pack2(a4, a5); o.w = pack2(a6, a7);
    *(uint4*)(out + (size_t)node * C_H + c8) = o;
}

// ================= fused layer: gather(A·H) -> LDS tile -> MFMA chain =================
template <bool FINAL>
__global__ void __launch_bounds__(256) fused_layer_kernel(
        const int* __restrict__ rowptr,
        const unsigned int* __restrict__ epay,
        const float* __restrict__ dinv,
        const unsigned short* __restrict__ hin,
        const unsigned short* __restrict__ Wp,
        const float* __restrict__ bias,
        const unsigned short* __restrict__ Wd1p,
        const float* __restrict__ bd1,
        const unsigned short* __restrict__ Wd2p,
        const float* __restrict__ bd2,
        unsigned short* __restrict__ out_b,
        float* __restrict__ out_f) {
    __shared__ unsigned short sG[16 * TSTRIDE];
    const int t = threadIdx.x;

    // ---- phase A: gather agg row into LDS tile, 8 edges in flight ----
    {
        int nl = t >> 4, c8 = (t & 15) << 3;
        int node = blockIdx.x * 16 + nl;
        float di = dinv[node], dii = di * di;
        uint4 raw = *(const uint4*)(hin + (size_t)node * C_H + c8);
        float a0 = bf_lo(raw.x) * dii, a1 = bf_hi(raw.x) * dii;
        float a2 = bf_lo(raw.y) * dii, a3 = bf_hi(raw.y) * dii;
        float a4 = bf_lo(raw.z) * dii, a5 = bf_hi(raw.z) * dii;
        float a6 = bf_lo(raw.w) * dii, a7 = bf_hi(raw.w) * dii;
        int beg = rowptr[node], end = rowptr[node + 1];
        int p = beg;
        for (; p + 8 <= end; p += 8) {
            uint4 ev0 = *(const uint4*)(epay + p);
            uint4 ev1 = *(const uint4*)(epay + p + 4);
            unsigned int ee[8] = {ev0.x, ev0.y, ev0.z, ev0.w, ev1.x, ev1.y, ev1.z, ev1.w};
            uint4 rv[8];
            #pragma unroll
            for (int j = 0; j < 8; ++j)
                rv[j] = *(const uint4*)(hin + (size_t)(ee[j] & 0xffffu) * C_H + c8);
            #pragma unroll
            for (int j = 0; j < 8; ++j) {
                float nm = h_bits2f((unsigned short)(ee[j] >> 16));
                a0 = fmaf(bf_lo(rv[j].x), nm, a0); a1 = fmaf(bf_hi(rv[j].x), nm, a1);
                a2 = fmaf(bf_lo(rv[j].y), nm, a2); a3 = fmaf(bf_hi(rv[j].y), nm, a3);
                a4 = fmaf(bf_lo(rv[j].z), nm, a4); a5 = fmaf(bf_hi(rv[j].z), nm, a5);
                a6 = fmaf(bf_lo(rv[j].w), nm, a6); a7 = fmaf(bf_hi(rv[j].w), nm, a7);
            }
        }
        if (p < end) {
            uint4 ev = *(const uint4*)(epay + p);
            unsigned int ee[4] = {ev.x, ev.y, ev.z, ev.w};
            uint4 rv[4];
            #pragma unroll
            for (int j = 0; j < 4; ++j)
                rv[j] = *(const uint4*)(hin + (size_t)(ee[j] & 0xffffu) * C_H + c8);
            #pragma unroll
            for (int j = 0; j < 4; ++j) {
                float nm = h_bits2f((unsigned short)(ee[j] >> 16));
                a0 = fmaf(bf_lo(rv[j].x), nm, a0); a1 = fmaf(bf_hi(rv[j].x), nm, a1);
                a2 = fmaf(bf_lo(rv[j].y), nm, a2); a3 = fmaf(bf_hi(rv[j].y), nm, a3);
                a4 = fmaf(bf_lo(rv[j].z), nm, a4); a5 = fmaf(bf_hi(rv[j].z), nm, a5);
                a6 = fmaf(bf_lo(rv[j].w), nm, a6); a7 = fmaf(bf_hi(rv[j].w), nm, a7);
            }
        }
        uint4 o;
        o.x = pack2(a0, a1); o.y = pack2(a2, a3);
        o.z = pack2(a4, a5); o.w = pack2(a6, a7);
        *(uint4*)(sG + nl * TSTRIDE + c8) = o;
    }
    __syncthreads();

    const int lane = t & 63, wave = t >> 6, quad = lane >> 4, row = lane & 15;
    const int node = blockIdx.x * 16 + row;

    // ---- mm1: tile @ Wp (COUT=128), bias+relu ----
    f32x4 acc0 = (f32x4){0.f, 0.f, 0.f, 0.f};
    f32x4 acc1 = (f32x4){0.f, 0.f, 0.f, 0.f};
    const int nb0 = 2 * wave, nb1 = 2 * wave + 1;
    #pragma unroll
    for (int kb = 0; kb < 4; ++kb) {
        bf16x8 hf = *(const bf16x8*)(sG + row * TSTRIDE + kb * 32 + quad * 8);
        bf16x8 wf0 = *(const bf16x8*)(Wp + ((size_t)(kb * 8 + nb0) * 64 + lane) * 8);
        bf16x8 wf1 = *(const bf16x8*)(Wp + ((size_t)(kb * 8 + nb1) * 64 + lane) * 8);
        acc0 = __builtin_amdgcn_mfma_f32_16x16x32_bf16(wf0, hf, acc0, 0, 0, 0);
        acc1 = __builtin_amdgcn_mfma_f32_16x16x32_bf16(wf1, hf, acc1, 0, 0, 0);
    }
    float4 ba0 = *(const float4*)(bias + nb0 * 16 + quad * 4);
    float4 ba1 = *(const float4*)(bias + nb1 * 16 + quad * 4);
    float v00 = fmaxf(acc0[0] + ba0.x, 0.f), v01 = fmaxf(acc0[1] + ba0.y, 0.f);
    float v02 = fmaxf(acc0[2] + ba0.z, 0.f), v03 = fmaxf(acc0[3] + ba0.w, 0.f);
    float v10 = fmaxf(acc1[0] + ba1.x, 0.f), v11 = fmaxf(acc1[1] + ba1.y, 0.f);
    float v12 = fmaxf(acc1[2] + ba1.z, 0.f), v13 = fmaxf(acc1[3] + ba1.w, 0.f);

    if (!FINAL) {
        uint2 o0, o1;
        o0.x = pack2(v00, v01); o0.y = pack2(v02, v03);
        o1.x = pack2(v10, v11); o1.y = pack2(v12, v13);
        *(uint2*)(out_b + (size_t)node * C_H + nb0 * 16 + quad * 4) = o0;
        *(uint2*)(out_b + (size_t)node * C_H + nb1 * 16 + quad * 4) = o1;
        return;
    }

    // ---- FINAL: H3 -> tile -> Wd1 -> tile -> Wd2 -> sigmoid -> out_f ----
    __syncthreads();
    {
        uint2 o0, o1;
        o0.x = pack2(v00, v01); o0.y = pack2(v02, v03);
        o1.x = pack2(v10, v11); o1.y = pack2(v12, v13);
        *(uint2*)(sG + row * TSTRIDE + nb0 * 16 + quad * 4) = o0;
        *(uint2*)(sG + row * TSTRIDE + nb1 * 16 + quad * 4) = o1;
    }
    __syncthreads();

    acc0 = (f32x4){0.f, 0.f, 0.f, 0.f};
    acc1 = (f32x4){0.f, 0.f, 0.f, 0.f};
    #pragma unroll
    for (int kb = 0; kb < 4; ++kb) {
        bf16x8 hf = *(const bf16x8*)(sG + row * TSTRIDE + kb * 32 + quad * 8);
        bf16x8 wf0 = *(const bf16x8*)(Wd1p + ((size_t)(kb * 8 + nb0) * 64 + lane) * 8);
        bf16x8 wf1 = *(const bf16x8*)(Wd1p + ((size_t)(kb * 8 + nb1) * 64 + lane) * 8);
        acc0 = __builtin_amdgcn_mfma_f32_16x16x32_bf16(wf0, hf, acc0, 0, 0, 0);
        acc1 = __builtin_amdgcn_mfma_f32_16x16x32_bf16(wf1, hf, acc1, 0, 0, 0);
    }
    ba0 = *(const float4*)(bd1 + nb0 * 16 + quad * 4);
    ba1 = *(const float4*)(bd1 + nb1 * 16 + quad * 4);
    v00 = fmaxf(acc0[0] + ba0.x, 0.f); v01 = fmaxf(acc0[1] + ba0.y, 0.f);
    v02 = fmaxf(acc0[2] + ba0.z, 0.f); v03 = fmaxf(acc0[3] + ba0.w, 0.f);
    v10 = fmaxf(acc1[0] + ba1.x, 0.f); v11 = fmaxf(acc1[1] + ba1.y, 0.f);
    v12 = fmaxf(acc1[2] + ba1.z, 0.f); v13 = fmaxf(acc1[3] + ba1.w, 0.f);
    __syncthreads();
    {
        uint2 o0, o1;
        o0.x = pack2(v00, v01); o0.y = pack2(v02, v03);
        o1.x = pack2(v10, v11); o1.y = pack2(v12, v13);
        *(uint2*)(sG + row * TSTRIDE + nb0 * 16 + quad * 4) = o0;
        *(uint2*)(sG + row * TSTRIDE + nb1 * 16 + quad * 4) = o1;
    }
    __syncthreads();

    f32x4 acc = (f32x4){0.f, 0.f, 0.f, 0.f};
    #pragma unroll
    for (int kb = 0; kb < 4; ++kb) {
        bf16x8 hf = *(const bf16x8*)(sG + row * TSTRIDE + kb * 32 + quad * 8);
        bf16x8 wf = *(const bf16x8*)(Wd2p + ((size_t)(kb * 4 + wave) * 64 + lane) * 8);
        acc = __builtin_amdgcn_mfma_f32_16x16x32_bf16(wf, hf, acc, 0, 0, 0);
    }
    int ch = wave * 16 + quad * 4;
    float4 b4 = *(const float4*)(bd2 + ch);
    float4 r;
    r.x = 1.f / (1.f + expf(-(acc[0] + b4.x)));
    r.y = 1.f / (1.f + expf(-(acc[1] + b4.y)));
    r.z = 1.f / (1.f + expf(-(acc[2] + b4.z)));
    r.w = 1.f / (1.f + expf(-(acc[3] + b4.w)));
    *(float4*)(out_f + (size_t)node * C_OUT + ch) = r;
}

extern "C" void kernel_launch(void* const* d_in, const int* in_sizes, int n_in,
                              void* d_out, int out_size, void* d_ws, size_t ws_size,
                              hipStream_t stream) {
    const float* x   = (const float*)d_in[0];
    const int*   ei  = (const int*)d_in[1];
    const float* W1  = (const float*)d_in[2];
    const float* b1  = (const float*)d_in[3];
    const float* W2  = (const float*)d_in[4];
    const float* b2  = (const float*)d_in[5];
    const float* W3  = (const float*)d_in[6];
    const float* b3  = (const float*)d_in[7];
    const float* Wd1 = (const float*)d_in[8];
    const float* bd1 = (const float*)d_in[9];
    const float* Wd2 = (const float*)d_in[10];
    const float* bd2 = (const float*)d_in[11];

    const int* src = ei;
    const int* dst = ei + N_EDGES;

    char* base = (char*)d_ws;
    size_t off = 0;
    auto alloc = [&](size_t bytes) { char* p = base + off; off += (bytes + 255) & ~size_t(255); return p; };
    int*            counts = (int*)alloc(50176 * 4);
    unsigned int*   epay   = (unsigned int*)alloc((size_t)E_PAD * 4);
    int*            rank   = (int*)alloc((size_t)N_EDGES * 4);
    float*          dinv   = (float*)alloc(N_NODES * 4);
    int*            rowptr = (int*)alloc((N_NODES + 1) * 4);
    int*            eblk   = (int*)alloc(N_NODES * 4);
    int*            bsum   = (int*)alloc(256 * 4);
    int*            bo     = (int*)alloc(256 * 4);
    unsigned short* XW1    = (unsigned short*)alloc((size_t)N_NODES * C_H * 2);
    unsigned short* bufA   = (unsigned short*)alloc((size_t)N_NODES * C_H * 2);
    unsigned short* bufB   = (unsigned short*)alloc((size_t)N_NODES * C_H * 2);
    unsigned short* P1     = (unsigned short*)alloc(128 * 128 * 2);
    unsigned short* P2     = (unsigned short*)alloc(128 * 128 * 2);
    unsigned short* P3     = (unsigned short*)alloc(128 * 128 * 2);
    unsigned short* Pd1    = (unsigned short*)alloc(128 * 128 * 2);
    unsigned short* Pd2    = (unsigned short*)alloc(128 * 64 * 2);

    const int T = 256;
    dim3 blk(T);
    dim3 gN((N_NODES + T - 1) / T);            // 196
    dim3 gPrep(3125 + 288 + 928);              // hist + pack + zero-epay
    dim3 gFillMM(MM_BLKS + 3125);              // mm + fill
    dim3 gFused(N_NODES / 16);                 // 3125, exact

    hipMemsetAsync(counts, 0, 50176 * 4, stream);
    prep_kernel<<<gPrep, blk, 0, stream>>>(dst, counts, rank,
                                           W1, W2, W3, Wd1, Wd2,
                                           P1, P2, P3, Pd1, Pd2, epay);
    scan1_kernel<<<gN, blk, 0, stream>>>(counts, eblk, bsum, dinv);
    scan2_kernel<<<1, blk, 0, stream>>>(bsum, bo, rowptr);
    scan3_kernel<<<gN, blk, 0, stream>>>(eblk, bo, rowptr);
    fill_mm_kernel<<<gFillMM, blk, 0, stream>>>(x, P1, XW1, src, dst, dinv,
                                                rowptr, rank, epay);

    // ---- layer 1: relu(agg(XW1) + b1) -> bufA (pure gather) ----
    gather1_kernel<<<gFused, blk, 0, stream>>>(rowptr, epay, dinv, XW1, b1, bufA);
    // ---- layer 2 ----
    fused_layer_kernel<false><<<gFused, blk, 0, stream>>>(
        rowptr, epay, dinv, bufA, P2, b2, nullptr, nullptr, nullptr, nullptr, bufB, nullptr);
    // ---- layer 3 + dense head ----
    fused_layer_kernel<true><<<gFused, blk, 0, stream>>>(
        rowptr, epay, dinv, bufB, P3, b3, Pd1, bd1, Pd2, bd2, nullptr, (float*)d_out);
}